// Round 3
// baseline (448.303 us; speedup 1.0000x reference)
//
#include <hip/hip_runtime.h>

typedef __attribute__((ext_vector_type(8))) short short8;
typedef __attribute__((ext_vector_type(4))) float f32x4;

#define BN 256
#define HD 128

__device__ __forceinline__ unsigned short f2bf(float f) {
    union { float f; unsigned int i; } v; v.f = f;
    unsigned int lsb = (v.i >> 16) & 1u;
    v.i += 0x7fffu + lsb;
    return (unsigned short)(v.i >> 16);
}
__device__ __forceinline__ float fsigmoid(float x) {
    return __builtin_amdgcn_rcpf(1.0f + __expf(-x));
}
__device__ __forceinline__ float fsilu(float x) {
    return x * fsigmoid(x);
}

// ---------------------------------------------------------------------------
// prep_w: transpose + bf16-convert edg2_w / cor2_w (128x128 f32) into ws so
// the main kernel's B-fragment loads (8 consecutive k for fixed n) are
// contiguous.  Wt[n][k] = bf16(W[k][n])
// ---------------------------------------------------------------------------
__global__ __launch_bounds__(256) void prep_w(const float* __restrict__ e2w,
                                              const float* __restrict__ c2w,
                                              unsigned short* __restrict__ WtE,
                                              unsigned short* __restrict__ WtC) {
    int n = blockIdx.x;          // 0..127 output row
    int t = threadIdx.x;         // 0..255
    if (t < 128) WtE[n * 128 + t] = f2bf(e2w[t * 128 + n]);
    else         WtC[n * 128 + (t - 128)] = f2bf(c2w[(t - 128) * 128 + n]);
}

// ---------------------------------------------------------------------------
// prep_A: A1e[r,k] = h[r]@edg1_w[0:128] + edg1_b ;  A2e[r,k] = h[r]@edg1_w[128:256]
//         A1c / A2c same with cor1_w/cor1_b.   r = b*256+i (2048 rows).
// ---------------------------------------------------------------------------
__global__ __launch_bounds__(128) void prep_A(const float* __restrict__ h,
                                              const float* __restrict__ e1w,
                                              const float* __restrict__ e1b,
                                              const float* __restrict__ c1w,
                                              const float* __restrict__ c1b,
                                              float* __restrict__ A1e, float* __restrict__ A2e,
                                              float* __restrict__ A1c, float* __restrict__ A2c) {
    int r0 = blockIdx.x * 8;
    int k  = threadIdx.x;
    __shared__ float hsl[8][HD];
    for (int r = 0; r < 8; ++r) hsl[r][k] = h[(r0 + r) * HD + k];
    __syncthreads();
    float s1[8] = {0,0,0,0,0,0,0,0}, s2[8] = {0,0,0,0,0,0,0,0};
    float s3[8] = {0,0,0,0,0,0,0,0}, s4[8] = {0,0,0,0,0,0,0,0};
    for (int f = 0; f < HD; ++f) {
        float w1 = e1w[f * HD + k];
        float w2 = e1w[(HD + f) * HD + k];
        float w3 = c1w[f * HD + k];
        float w4 = c1w[(HD + f) * HD + k];
#pragma unroll
        for (int r = 0; r < 8; ++r) {
            float hv = hsl[r][f];
            s1[r] += hv * w1; s2[r] += hv * w2; s3[r] += hv * w3; s4[r] += hv * w4;
        }
    }
    float be = e1b[k], bc = c1b[k];
    for (int r = 0; r < 8; ++r) {
        A1e[(r0 + r) * HD + k] = s1[r] + be;
        A2e[(r0 + r) * HD + k] = s2[r];
        A1c[(r0 + r) * HD + k] = s3[r] + bc;
        A2c[(r0 + r) * HD + k] = s4[r];
    }
}

// ---------------------------------------------------------------------------
// Main fused kernel: one workgroup per (b,i).
// ---------------------------------------------------------------------------
__global__ __launch_bounds__(256, 1) void egc_main(
    const float* __restrict__ x, const float* __restrict__ h,
    const float* __restrict__ x0, const float* __restrict__ pmask,
    const float* __restrict__ e1w,                                    // rows 256/257 = d2/d02 weights
    const float* __restrict__ e2b, const float* __restrict__ eiw,
    const float* __restrict__ eib,
    const float* __restrict__ n1w, const float* __restrict__ n1b,
    const float* __restrict__ n2w, const float* __restrict__ n2b,
    const float* __restrict__ c1w, const float* __restrict__ c2b,
    const float* __restrict__ c3w, const float* __restrict__ c3b,
    const float* __restrict__ A1e, const float* __restrict__ A2e,
    const float* __restrict__ A1c, const float* __restrict__ A2c,
    const unsigned short* __restrict__ WtE, const unsigned short* __restrict__ WtC,
    float* __restrict__ xout, float* __restrict__ hout) {

    __shared__ __align__(16) unsigned short tbuf[BN * HD];   // 64 KB, XOR-swizzled
    __shared__ __align__(16) float xs[BN][4];
    __shared__ __align__(16) float x0s[BN][4];
    __shared__ __align__(16) float d2s[BN], d02s[BN], rsh[BN];
    __shared__ __align__(16) float vE0[HD], vE1[HD], vE2[HD]; // A1e(i)+b1, w_d2, w_d02
    __shared__ __align__(16) float vC0[HD], vC1[HD], vC2[HD];
    __shared__ __align__(16) float hsv[HD];
    __shared__ __align__(16) float aggbuf[4][HD];
    __shared__ __align__(16) float aggv[HD];
    __shared__ float updbuf[4][4];
    __shared__ float smask;

    const int tid = threadIdx.x;
    const int bi  = blockIdx.x;         // 0..2047
    const int b   = bi >> 8;
    const int i   = bi & 255;
    const int row = bi;                 // global row b*256+i

    // ---- setup loads ----
    {
        int gj = b * BN + tid;
        xs[tid][0]  = x[gj * 3 + 0];
        xs[tid][1]  = x[gj * 3 + 1];
        xs[tid][2]  = x[gj * 3 + 2];
        x0s[tid][0] = x0[gj * 3 + 0];
        x0s[tid][1] = x0[gj * 3 + 1];
        x0s[tid][2] = x0[gj * 3 + 2];
    }
    if (tid < HD) {
        vE0[tid] = A1e[row * HD + tid];
        vE1[tid] = e1w[256 * HD + tid];
        vE2[tid] = e1w[257 * HD + tid];
        hsv[tid] = h[row * HD + tid];
    } else {
        int t = tid - HD;
        vC0[t] = A1c[row * HD + t];
        vC1[t] = c1w[256 * HD + t];
        vC2[t] = c1w[257 * HD + t];
    }
    if (tid == 0) smask = pmask[row];
    __syncthreads();

    // ---- pairwise distances vs row i ----
    {
        float dx = xs[i][0] - xs[tid][0];
        float dy = xs[i][1] - xs[tid][1];
        float dz = xs[i][2] - xs[tid][2];
        float d2 = dx * dx + dy * dy + dz * dz;
        d2s[tid] = d2;
        float dist = (d2 > 0.0f) ? sqrtf(d2) : 0.0f;
        rsh[tid] = __builtin_amdgcn_rcpf(dist + 1.0f);
        float ex = x0s[i][0] - x0s[tid][0];
        float ey = x0s[i][1] - x0s[tid][1];
        float ez = x0s[i][2] - x0s[tid][2];
        d02s[tid] = ex * ex + ey * ey + ez * ez;
    }
    __syncthreads();

    const int lane = tid & 63, wv = tid >> 6;
    const int c = lane & 15, q = lane >> 4;

    // =================== EDGE PATH ===================
    // E1: t[j,k] = silu(A1e_i[k] + A2e[j,k] + d2*wd2[k] + d02*wd02[k])
    {
        const float* A2g = A2e + (size_t)b * BN * HD;
#pragma unroll 4
        for (int it = 0; it < 32; ++it) {
            int f4 = it * 256 + tid;
            int j  = f4 >> 5;
            int k4 = (f4 & 31) << 2;
            float4 a2 = *((const float4*)A2g + f4);
            float d2v = d2s[j], d02v = d02s[j];
            float4 v0 = *(const float4*)(vE0 + k4);
            float4 v1 = *(const float4*)(vE1 + k4);
            float4 v2 = *(const float4*)(vE2 + k4);
            ushort4 o;
            o.x = f2bf(fsilu(a2.x + v0.x + d2v * v1.x + d02v * v2.x));
            o.y = f2bf(fsilu(a2.y + v0.y + d2v * v1.y + d02v * v2.y));
            o.z = f2bf(fsilu(a2.z + v0.z + d2v * v1.z + d02v * v2.z));
            o.w = f2bf(fsilu(a2.w + v0.w + d2v * v1.w + d02v * v2.w));
            int blk = (k4 >> 3) ^ (j & 7);
            *(ushort4*)(tbuf + j * HD + blk * 8 + (k4 & 7)) = o;
        }
    }
    __syncthreads();

    // E2: m = silu(t @ W2e + b2e); e = sigmoid(m@wI + bI); agg = mean_j(e*m)
    {
        float b2l[8], wIl[8];
#pragma unroll
        for (int nt = 0; nt < 8; ++nt) {
            b2l[nt] = e2b[nt * 16 + c];
            wIl[nt] = eiw[nt * 16 + c];
        }
        float bI = eib[0];
        short8 Bf[8][4];
#pragma unroll
        for (int nt = 0; nt < 8; ++nt)
#pragma unroll
            for (int ks = 0; ks < 4; ++ks)
                Bf[nt][ks] = *(const short8*)(WtE + (nt * 16 + c) * HD + ks * 32 + q * 8);
        f32x4 acc[4][8];
        const f32x4 zf = {0.f, 0.f, 0.f, 0.f};
#pragma unroll
        for (int mt = 0; mt < 4; ++mt)
#pragma unroll
            for (int nt = 0; nt < 8; ++nt) acc[mt][nt] = zf;
#pragma unroll
        for (int ks = 0; ks < 4; ++ks) {
            short8 Af[4];
#pragma unroll
            for (int mt = 0; mt < 4; ++mt) {
                int r  = wv * 64 + mt * 16 + c;
                int kb = ks * 32 + q * 8;
                int blk = (kb >> 3) ^ (r & 7);
                Af[mt] = *(const short8*)(tbuf + r * HD + blk * 8);
            }
#pragma unroll
            for (int mt = 0; mt < 4; ++mt)
#pragma unroll
                for (int nt = 0; nt < 8; ++nt)
                    acc[mt][nt] = __builtin_amdgcn_mfma_f32_16x16x32_bf16(Af[mt], Bf[nt][ks], acc[mt][nt], 0, 0, 0);
        }
        // epilogue: gate + aggregate
        float aggp[8] = {0,0,0,0,0,0,0,0};
#pragma unroll
        for (int mt = 0; mt < 4; ++mt) {
#pragma unroll
            for (int reg = 0; reg < 4; ++reg) {
                int r = wv * 64 + mt * 16 + q * 4 + reg;
                float mv[8]; float ed = 0.f;
#pragma unroll
                for (int nt = 0; nt < 8; ++nt) {
                    mv[nt] = fsilu(acc[mt][nt][reg] + b2l[nt]);
                    ed += mv[nt] * wIl[nt];
                }
                ed += __shfl_xor(ed, 1);
                ed += __shfl_xor(ed, 2);
                ed += __shfl_xor(ed, 4);
                ed += __shfl_xor(ed, 8);
                float e = (r == i) ? 0.0f : fsigmoid(ed + bI);
#pragma unroll
                for (int nt = 0; nt < 8; ++nt) aggp[nt] += e * mv[nt];
            }
        }
#pragma unroll
        for (int nt = 0; nt < 8; ++nt) {
            aggp[nt] += __shfl_xor(aggp[nt], 16);
            aggp[nt] += __shfl_xor(aggp[nt], 32);
        }
        if (q == 0)
#pragma unroll
            for (int nt = 0; nt < 8; ++nt) aggbuf[wv][nt * 16 + c] = aggp[nt];
    }
    __syncthreads();
    if (tid < HD)
        aggv[tid] = (aggbuf[0][tid] + aggbuf[1][tid] + aggbuf[2][tid] + aggbuf[3][tid]) * (1.0f / 256.0f);
    __syncthreads();

    // =================== COORD PATH ===================
    // C1: u[j,k] = silu(A1c_i[k] + A2c[j,k] + d2*wd2c[k] + d02*wd02c[k])
    {
        const float* A2g = A2c + (size_t)b * BN * HD;
#pragma unroll 4
        for (int it = 0; it < 32; ++it) {
            int f4 = it * 256 + tid;
            int j  = f4 >> 5;
            int k4 = (f4 & 31) << 2;
            float4 a2 = *((const float4*)A2g + f4);
            float d2v = d2s[j], d02v = d02s[j];
            float4 v0 = *(const float4*)(vC0 + k4);
            float4 v1 = *(const float4*)(vC1 + k4);
            float4 v2 = *(const float4*)(vC2 + k4);
            ushort4 o;
            o.x = f2bf(fsilu(a2.x + v0.x + d2v * v1.x + d02v * v2.x));
            o.y = f2bf(fsilu(a2.y + v0.y + d2v * v1.y + d02v * v2.y));
            o.z = f2bf(fsilu(a2.z + v0.z + d2v * v1.z + d02v * v2.z));
            o.w = f2bf(fsilu(a2.w + v0.w + d2v * v1.w + d02v * v2.w));
            int blk = (k4 >> 3) ^ (j & 7);
            *(ushort4*)(tbuf + j * HD + blk * 8 + (k4 & 7)) = o;
        }
    }
    __syncthreads();

    // C2: cvec = silu(u @ W2c + b2c); cw = cvec@w3 + b3; upd = mean_j cw*shift
    {
        float b2l[8], w3l[8];
#pragma unroll
        for (int nt = 0; nt < 8; ++nt) {
            b2l[nt] = c2b[nt * 16 + c];
            w3l[nt] = c3w[nt * 16 + c];
        }
        float b3 = c3b[0];
        short8 Bf[8][4];
#pragma unroll
        for (int nt = 0; nt < 8; ++nt)
#pragma unroll
            for (int ks = 0; ks < 4; ++ks)
                Bf[nt][ks] = *(const short8*)(WtC + (nt * 16 + c) * HD + ks * 32 + q * 8);
        f32x4 acc[4][8];
        const f32x4 zf = {0.f, 0.f, 0.f, 0.f};
#pragma unroll
        for (int mt = 0; mt < 4; ++mt)
#pragma unroll
            for (int nt = 0; nt < 8; ++nt) acc[mt][nt] = zf;
#pragma unroll
        for (int ks = 0; ks < 4; ++ks) {
            short8 Af[4];
#pragma unroll
            for (int mt = 0; mt < 4; ++mt) {
                int r  = wv * 64 + mt * 16 + c;
                int kb = ks * 32 + q * 8;
                int blk = (kb >> 3) ^ (r & 7);
                Af[mt] = *(const short8*)(tbuf + r * HD + blk * 8);
            }
#pragma unroll
            for (int mt = 0; mt < 4; ++mt)
#pragma unroll
                for (int nt = 0; nt < 8; ++nt)
                    acc[mt][nt] = __builtin_amdgcn_mfma_f32_16x16x32_bf16(Af[mt], Bf[nt][ks], acc[mt][nt], 0, 0, 0);
        }
        float updp = 0.f;
        float xic = (c < 3) ? xs[i][c] : 0.f;
#pragma unroll
        for (int mt = 0; mt < 4; ++mt) {
#pragma unroll
            for (int reg = 0; reg < 4; ++reg) {
                int r = wv * 64 + mt * 16 + q * 4 + reg;
                float cd = 0.f;
#pragma unroll
                for (int nt = 0; nt < 8; ++nt)
                    cd += fsilu(acc[mt][nt][reg] + b2l[nt]) * w3l[nt];
                cd += __shfl_xor(cd, 1);
                cd += __shfl_xor(cd, 2);
                cd += __shfl_xor(cd, 4);
                cd += __shfl_xor(cd, 8);
                float cw = cd + b3;
                if (c < 3 && r != i)
                    updp += cw * (xic - xs[r][c]) * rsh[r];
            }
        }
        updp += __shfl_xor(updp, 16);
        updp += __shfl_xor(updp, 32);
        if (q == 0 && c < 3) updbuf[wv][c] = updp;
    }
    __syncthreads();

    // x output (float32)
    if (tid < 3) {
        float u = (updbuf[0][tid] + updbuf[1][tid] + updbuf[2][tid] + updbuf[3][tid]) * (1.0f / 256.0f);
        float xo = (xs[i][tid] + u) * smask;
        xout[row * 3 + tid] = xo;
    }

    // =================== NODE MLP ===================
    // h_next = (h + silu([h,agg]@W1 + b1)@W2 + b2) * mask
    float* npart = (float*)tbuf;       // reuse LDS
    {
        int k = tid & 127, half = tid >> 7;
        const float* wp = n1w + (size_t)half * HD * HD + k;
        float s = 0.f;
#pragma unroll 4
        for (int f = 0; f < HD; ++f) {
            float nin = half ? aggv[f] : hsv[f];
            s += nin * wp[f * HD];
        }
        npart[half * HD + k] = s;
    }
    __syncthreads();
    float* qv = npart + 2 * HD;
    if (tid < HD)
        qv[tid] = fsilu(npart[tid] + npart[HD + tid] + n1b[tid]);
    __syncthreads();
    if (tid < HD) {
        float s = 0.f;
#pragma unroll 4
        for (int f = 0; f < HD; ++f) s += qv[f] * n2w[f * HD + tid];
        float hn = (hsv[tid] + s + n2b[tid]) * smask;
        hout[(size_t)row * HD + tid] = hn;
    }
}

extern "C" void kernel_launch(void* const* d_in, const int* in_sizes, int n_in,
                              void* d_out, int out_size, void* d_ws, size_t ws_size,
                              hipStream_t stream) {
    const float* x    = (const float*)d_in[0];
    const float* h    = (const float*)d_in[1];
    const float* x0   = (const float*)d_in[2];
    const float* pm   = (const float*)d_in[3];
    const float* e1w  = (const float*)d_in[4];
    const float* e1b  = (const float*)d_in[5];
    const float* e2w  = (const float*)d_in[6];
    const float* e2b  = (const float*)d_in[7];
    const float* eiw  = (const float*)d_in[8];
    const float* eib  = (const float*)d_in[9];
    const float* n1w  = (const float*)d_in[10];
    const float* n1b  = (const float*)d_in[11];
    const float* n2w  = (const float*)d_in[12];
    const float* n2b  = (const float*)d_in[13];
    const float* c1w  = (const float*)d_in[14];
    const float* c1b  = (const float*)d_in[15];
    const float* c2w  = (const float*)d_in[16];
    const float* c2b  = (const float*)d_in[17];
    const float* c3w  = (const float*)d_in[18];
    const float* c3b  = (const float*)d_in[19];

    float* wsf = (float*)d_ws;
    const size_t nA = 2048 * 128;
    float* A1e = wsf;
    float* A2e = wsf + nA;
    float* A1c = wsf + 2 * nA;
    float* A2c = wsf + 3 * nA;
    unsigned short* WtE = (unsigned short*)(wsf + 4 * nA);
    unsigned short* WtC = WtE + 128 * 128;

    float* xout = (float*)d_out;
    float* hout = xout + 8 * 256 * 3;

    prep_w<<<dim3(128), dim3(256), 0, stream>>>(e2w, c2w, WtE, WtC);
    prep_A<<<dim3(256), dim3(128), 0, stream>>>(h, e1w, e1b, c1w, c1b, A1e, A2e, A1c, A2c);
    egc_main<<<dim3(2048), dim3(256), 0, stream>>>(
        x, h, x0, pm, e1w, e2b, eiw, eib, n1w, n1b, n2w, n2b,
        c1w, c2b, c3w, c3b, A1e, A2e, A1c, A2c, WtE, WtC, xout, hout);
}

// Round 4
// 395.916 us; speedup vs baseline: 1.1323x; 1.1323x over previous
//
#include <hip/hip_runtime.h>

typedef __attribute__((ext_vector_type(8))) short short8;
typedef __attribute__((ext_vector_type(4))) float f32x4;

#define BN 256
#define HD 128

__device__ __forceinline__ unsigned short f2bf(float f) {
    union { float f; unsigned int i; } v; v.f = f;
    unsigned int lsb = (v.i >> 16) & 1u;
    v.i += 0x7fffu + lsb;
    return (unsigned short)(v.i >> 16);
}
__device__ __forceinline__ float fsigmoid(float x) {
    return __builtin_amdgcn_rcpf(1.0f + __expf(-x));
}
__device__ __forceinline__ float fsilu(float x) {
    return x * fsigmoid(x);
}

// ---------------------------------------------------------------------------
// prep_w: transpose + bf16-convert edg2_w / cor2_w (128x128 f32) into ws.
// Wt[n][k] = bf16(W[k][n])
// ---------------------------------------------------------------------------
__global__ __launch_bounds__(256) void prep_w(const float* __restrict__ e2w,
                                              const float* __restrict__ c2w,
                                              unsigned short* __restrict__ WtE,
                                              unsigned short* __restrict__ WtC) {
    int n = blockIdx.x;          // 0..127 output row
    int t = threadIdx.x;         // 0..255
    if (t < 128) WtE[n * 128 + t] = f2bf(e2w[t * 128 + n]);
    else         WtC[n * 128 + (t - 128)] = f2bf(c2w[(t - 128) * 128 + n]);
}

// ---------------------------------------------------------------------------
// prep_A v2: 512 blocks x 256 threads; block handles 4 rows; grp 0 -> edge
// weights, grp 1 -> coord weights. 2 blocks/CU resident.
// ---------------------------------------------------------------------------
__global__ __launch_bounds__(256) void prep_A(const float* __restrict__ h,
                                              const float* __restrict__ e1w,
                                              const float* __restrict__ e1b,
                                              const float* __restrict__ c1w,
                                              const float* __restrict__ c1b,
                                              float* __restrict__ A1e, float* __restrict__ A2e,
                                              float* __restrict__ A1c, float* __restrict__ A2c) {
    int r0 = blockIdx.x * 4;
    int k   = threadIdx.x & 127;
    int grp = threadIdx.x >> 7;            // 0: edge, 1: coord
    __shared__ float hsl[4][HD];
    {
        int rr = threadIdx.x >> 7;         // 0..1
        hsl[rr][k]     = h[(r0 + rr) * HD + k];
        hsl[rr + 2][k] = h[(r0 + rr + 2) * HD + k];
    }
    __syncthreads();
    const float* W = grp ? c1w : e1w;
    float s1[4] = {0,0,0,0}, s2[4] = {0,0,0,0};
#pragma unroll 4
    for (int f = 0; f < HD; ++f) {
        float w1 = W[f * HD + k];
        float w2 = W[(HD + f) * HD + k];
#pragma unroll
        for (int r = 0; r < 4; ++r) {
            float hv = hsl[r][f];
            s1[r] += hv * w1; s2[r] += hv * w2;
        }
    }
    float bb = grp ? c1b[k] : e1b[k];
    float* O1 = grp ? A1c : A1e;
    float* O2 = grp ? A2c : A2e;
#pragma unroll
    for (int r = 0; r < 4; ++r) {
        O1[(r0 + r) * HD + k] = s1[r] + bb;
        O2[(r0 + r) * HD + k] = s2[r];
    }
}

// ---------------------------------------------------------------------------
// Main fused kernel: one workgroup (512 thr, 8 waves) per (b,i).
// A-fragments computed directly in registers (no tbuf LDS round-trip).
// ---------------------------------------------------------------------------
__global__ __launch_bounds__(512, 4) void egc_main(
    const float* __restrict__ x, const float* __restrict__ h,
    const float* __restrict__ x0, const float* __restrict__ pmask,
    const float* __restrict__ e1w,
    const float* __restrict__ e2b, const float* __restrict__ eiw,
    const float* __restrict__ eib,
    const float* __restrict__ n1w, const float* __restrict__ n1b,
    const float* __restrict__ n2w, const float* __restrict__ n2b,
    const float* __restrict__ c1w, const float* __restrict__ c2b,
    const float* __restrict__ c3w, const float* __restrict__ c3b,
    const float* __restrict__ A1e, const float* __restrict__ A2e,
    const float* __restrict__ A1c, const float* __restrict__ A2c,
    const unsigned short* __restrict__ WtE, const unsigned short* __restrict__ WtC,
    float* __restrict__ xout, float* __restrict__ hout) {

    __shared__ __align__(16) float xs[BN][4];
    __shared__ __align__(16) float x0s[BN][4];
    __shared__ __align__(16) float d2s[BN], d02s[BN], rsh[BN];
    __shared__ __align__(16) float vE0[HD], vE1[HD], vE2[HD];
    __shared__ __align__(16) float vC0[HD], vC1[HD], vC2[HD];
    __shared__ __align__(16) float hsv[HD];
    __shared__ __align__(16) float aggbuf[8][HD];   // also reused as npart/qv
    __shared__ __align__(16) float aggv[HD];
    __shared__ float updbuf[8][4];
    __shared__ float smask;

    const int tid = threadIdx.x;
    const int bi  = blockIdx.x;         // 0..2047
    const int b   = bi >> 8;
    const int i   = bi & 255;
    const int row = bi;

    // ---- setup loads ----
    if (tid < BN) {
        int gj = b * BN + tid;
        xs[tid][0]  = x[gj * 3 + 0];
        xs[tid][1]  = x[gj * 3 + 1];
        xs[tid][2]  = x[gj * 3 + 2];
        x0s[tid][0] = x0[gj * 3 + 0];
        x0s[tid][1] = x0[gj * 3 + 1];
        x0s[tid][2] = x0[gj * 3 + 2];
    }
    if (tid < HD) {
        vE0[tid] = A1e[row * HD + tid];
        vE1[tid] = e1w[256 * HD + tid];
        vE2[tid] = e1w[257 * HD + tid];
    } else if (tid < 2 * HD) {
        int t = tid - HD;
        vC0[t] = A1c[row * HD + t];
        vC1[t] = c1w[256 * HD + t];
        vC2[t] = c1w[257 * HD + t];
    } else if (tid < 3 * HD) {
        int t = tid - 2 * HD;
        hsv[t] = h[row * HD + t];
    }
    if (tid == 0) smask = pmask[row];
    __syncthreads();

    // ---- pairwise distances vs row i ----
    if (tid < BN) {
        float dx = xs[i][0] - xs[tid][0];
        float dy = xs[i][1] - xs[tid][1];
        float dz = xs[i][2] - xs[tid][2];
        float d2 = dx * dx + dy * dy + dz * dz;
        d2s[tid] = d2;
        float dist = (d2 > 0.0f) ? sqrtf(d2) : 0.0f;
        rsh[tid] = __builtin_amdgcn_rcpf(dist + 1.0f);
        float ex = x0s[i][0] - x0s[tid][0];
        float ey = x0s[i][1] - x0s[tid][1];
        float ez = x0s[i][2] - x0s[tid][2];
        d02s[tid] = ex * ex + ey * ey + ez * ez;
    }
    __syncthreads();

    const int lane = tid & 63, wv = tid >> 6;   // 8 waves
    const int c = lane & 15, q = lane >> 4;

    // =================== EDGE PATH ===================
    {
        const float* A2g = A2e + (size_t)b * BN * HD;
        f32x4 acc[2][8];
        const f32x4 zf = {0.f, 0.f, 0.f, 0.f};
#pragma unroll
        for (int mt = 0; mt < 2; ++mt)
#pragma unroll
            for (int nt = 0; nt < 8; ++nt) acc[mt][nt] = zf;
#pragma unroll
        for (int ks = 0; ks < 4; ++ks) {
            const int kb = ks * 32 + q * 8;
            short8 Af[2];
#pragma unroll
            for (int mt = 0; mt < 2; ++mt) {
                int r = wv * 32 + mt * 16 + c;
                float4 alo = *(const float4*)(A2g + r * HD + kb);
                float4 ahi = *(const float4*)(A2g + r * HD + kb + 4);
                float d2v = d2s[r], d02v = d02s[r];
                float4 p0 = *(const float4*)(vE0 + kb);
                float4 p0h = *(const float4*)(vE0 + kb + 4);
                float4 p1 = *(const float4*)(vE1 + kb);
                float4 p1h = *(const float4*)(vE1 + kb + 4);
                float4 p2 = *(const float4*)(vE2 + kb);
                float4 p2h = *(const float4*)(vE2 + kb + 4);
                short8 af;
                af[0] = (short)f2bf(fsilu(alo.x + p0.x + d2v * p1.x + d02v * p2.x));
                af[1] = (short)f2bf(fsilu(alo.y + p0.y + d2v * p1.y + d02v * p2.y));
                af[2] = (short)f2bf(fsilu(alo.z + p0.z + d2v * p1.z + d02v * p2.z));
                af[3] = (short)f2bf(fsilu(alo.w + p0.w + d2v * p1.w + d02v * p2.w));
                af[4] = (short)f2bf(fsilu(ahi.x + p0h.x + d2v * p1h.x + d02v * p2h.x));
                af[5] = (short)f2bf(fsilu(ahi.y + p0h.y + d2v * p1h.y + d02v * p2h.y));
                af[6] = (short)f2bf(fsilu(ahi.z + p0h.z + d2v * p1h.z + d02v * p2h.z));
                af[7] = (short)f2bf(fsilu(ahi.w + p0h.w + d2v * p1h.w + d02v * p2h.w));
                Af[mt] = af;
            }
#pragma unroll
            for (int nt = 0; nt < 8; ++nt) {
                short8 Bf = *(const short8*)(WtE + (nt * 16 + c) * HD + kb);
                acc[0][nt] = __builtin_amdgcn_mfma_f32_16x16x32_bf16(Af[0], Bf, acc[0][nt], 0, 0, 0);
                acc[1][nt] = __builtin_amdgcn_mfma_f32_16x16x32_bf16(Af[1], Bf, acc[1][nt], 0, 0, 0);
            }
        }
        // epilogue: gate + aggregate
        float b2l[8], wIl[8];
#pragma unroll
        for (int nt = 0; nt < 8; ++nt) {
            b2l[nt] = e2b[nt * 16 + c];
            wIl[nt] = eiw[nt * 16 + c];
        }
        float bI = eib[0];
        float aggp[8] = {0,0,0,0,0,0,0,0};
#pragma unroll
        for (int mt = 0; mt < 2; ++mt) {
#pragma unroll
            for (int reg = 0; reg < 4; ++reg) {
                int r = wv * 32 + mt * 16 + q * 4 + reg;
                float mv[8]; float ed = 0.f;
#pragma unroll
                for (int nt = 0; nt < 8; ++nt) {
                    mv[nt] = fsilu(acc[mt][nt][reg] + b2l[nt]);
                    ed += mv[nt] * wIl[nt];
                }
                ed += __shfl_xor(ed, 1);
                ed += __shfl_xor(ed, 2);
                ed += __shfl_xor(ed, 4);
                ed += __shfl_xor(ed, 8);
                float e = (r == i) ? 0.0f : fsigmoid(ed + bI);
#pragma unroll
                for (int nt = 0; nt < 8; ++nt) aggp[nt] += e * mv[nt];
            }
        }
#pragma unroll
        for (int nt = 0; nt < 8; ++nt) {
            aggp[nt] += __shfl_xor(aggp[nt], 16);
            aggp[nt] += __shfl_xor(aggp[nt], 32);
        }
        if (q == 0)
#pragma unroll
            for (int nt = 0; nt < 8; ++nt) aggbuf[wv][nt * 16 + c] = aggp[nt];
    }
    __syncthreads();
    if (tid < HD) {
        float s = 0.f;
#pragma unroll
        for (int w = 0; w < 8; ++w) s += aggbuf[w][tid];
        aggv[tid] = s * (1.0f / 256.0f);
    }
    __syncthreads();

    // =================== COORD PATH ===================
    {
        const float* A2g = A2c + (size_t)b * BN * HD;
        f32x4 acc[2][8];
        const f32x4 zf = {0.f, 0.f, 0.f, 0.f};
#pragma unroll
        for (int mt = 0; mt < 2; ++mt)
#pragma unroll
            for (int nt = 0; nt < 8; ++nt) acc[mt][nt] = zf;
#pragma unroll
        for (int ks = 0; ks < 4; ++ks) {
            const int kb = ks * 32 + q * 8;
            short8 Af[2];
#pragma unroll
            for (int mt = 0; mt < 2; ++mt) {
                int r = wv * 32 + mt * 16 + c;
                float4 alo = *(const float4*)(A2g + r * HD + kb);
                float4 ahi = *(const float4*)(A2g + r * HD + kb + 4);
                float d2v = d2s[r], d02v = d02s[r];
                float4 p0 = *(const float4*)(vC0 + kb);
                float4 p0h = *(const float4*)(vC0 + kb + 4);
                float4 p1 = *(const float4*)(vC1 + kb);
                float4 p1h = *(const float4*)(vC1 + kb + 4);
                float4 p2 = *(const float4*)(vC2 + kb);
                float4 p2h = *(const float4*)(vC2 + kb + 4);
                short8 af;
                af[0] = (short)f2bf(fsilu(alo.x + p0.x + d2v * p1.x + d02v * p2.x));
                af[1] = (short)f2bf(fsilu(alo.y + p0.y + d2v * p1.y + d02v * p2.y));
                af[2] = (short)f2bf(fsilu(alo.z + p0.z + d2v * p1.z + d02v * p2.z));
                af[3] = (short)f2bf(fsilu(alo.w + p0.w + d2v * p1.w + d02v * p2.w));
                af[4] = (short)f2bf(fsilu(ahi.x + p0h.x + d2v * p1h.x + d02v * p2h.x));
                af[5] = (short)f2bf(fsilu(ahi.y + p0h.y + d2v * p1h.y + d02v * p2h.y));
                af[6] = (short)f2bf(fsilu(ahi.z + p0h.z + d2v * p1h.z + d02v * p2h.z));
                af[7] = (short)f2bf(fsilu(ahi.w + p0h.w + d2v * p1h.w + d02v * p2h.w));
                Af[mt] = af;
            }
#pragma unroll
            for (int nt = 0; nt < 8; ++nt) {
                short8 Bf = *(const short8*)(WtC + (nt * 16 + c) * HD + kb);
                acc[0][nt] = __builtin_amdgcn_mfma_f32_16x16x32_bf16(Af[0], Bf, acc[0][nt], 0, 0, 0);
                acc[1][nt] = __builtin_amdgcn_mfma_f32_16x16x32_bf16(Af[1], Bf, acc[1][nt], 0, 0, 0);
            }
        }
        float b2l[8], w3l[8];
#pragma unroll
        for (int nt = 0; nt < 8; ++nt) {
            b2l[nt] = c2b[nt * 16 + c];
            w3l[nt] = c3w[nt * 16 + c];
        }
        float b3 = c3b[0];
        float updp = 0.f;
        float xic = (c < 3) ? xs[i][c] : 0.f;
#pragma unroll
        for (int mt = 0; mt < 2; ++mt) {
#pragma unroll
            for (int reg = 0; reg < 4; ++reg) {
                int r = wv * 32 + mt * 16 + q * 4 + reg;
                float cd = 0.f;
#pragma unroll
                for (int nt = 0; nt < 8; ++nt)
                    cd += fsilu(acc[mt][nt][reg] + b2l[nt]) * w3l[nt];
                cd += __shfl_xor(cd, 1);
                cd += __shfl_xor(cd, 2);
                cd += __shfl_xor(cd, 4);
                cd += __shfl_xor(cd, 8);
                float cw = cd + b3;
                if (c < 3 && r != i)
                    updp += cw * (xic - xs[r][c]) * rsh[r];
            }
        }
        updp += __shfl_xor(updp, 16);
        updp += __shfl_xor(updp, 32);
        if (q == 0 && c < 3) updbuf[wv][c] = updp;
    }
    __syncthreads();

    // x output (float32)
    if (tid < 3) {
        float u = 0.f;
#pragma unroll
        for (int w = 0; w < 8; ++w) u += updbuf[w][tid];
        u *= (1.0f / 256.0f);
        xout[row * 3 + tid] = (xs[i][tid] + u) * smask;
    }

    // =================== NODE MLP ===================
    // h_next = (h + silu([h,agg]@W1 + b1)@W2 + b2) * mask
    float* npart = &aggbuf[0][0];           // reuse (aggv already extracted)
    float* qv    = npart + 4 * HD;
    {
        int k = tid & 127, part = tid >> 7;        // 0..3
        int fbase = (part & 1) * 64;
        int wbase = (part >> 1) * HD;              // 0 for h, 128 for agg
        const float* src = (part >> 1) ? aggv : hsv;
        float s = 0.f;
#pragma unroll 4
        for (int f = 0; f < 64; ++f) {
            int ff = fbase + f;
            s += src[ff] * n1w[(wbase + ff) * HD + k];
        }
        npart[part * HD + k] = s;
    }
    __syncthreads();
    if (tid < HD)
        qv[tid] = fsilu(npart[tid] + npart[HD + tid] + npart[2 * HD + tid] + npart[3 * HD + tid] + n1b[tid]);
    __syncthreads();
    if (tid < HD) {
        float s = 0.f;
#pragma unroll 4
        for (int f = 0; f < HD; ++f) s += qv[f] * n2w[f * HD + tid];
        hout[(size_t)row * HD + tid] = (hsv[tid] + s + n2b[tid]) * smask;
    }
}

extern "C" void kernel_launch(void* const* d_in, const int* in_sizes, int n_in,
                              void* d_out, int out_size, void* d_ws, size_t ws_size,
                              hipStream_t stream) {
    const float* x    = (const float*)d_in[0];
    const float* h    = (const float*)d_in[1];
    const float* x0   = (const float*)d_in[2];
    const float* pm   = (const float*)d_in[3];
    const float* e1w  = (const float*)d_in[4];
    const float* e1b  = (const float*)d_in[5];
    const float* e2w  = (const float*)d_in[6];
    const float* e2b  = (const float*)d_in[7];
    const float* eiw  = (const float*)d_in[8];
    const float* eib  = (const float*)d_in[9];
    const float* n1w  = (const float*)d_in[10];
    const float* n1b  = (const float*)d_in[11];
    const float* n2w  = (const float*)d_in[12];
    const float* n2b  = (const float*)d_in[13];
    const float* c1w  = (const float*)d_in[14];
    const float* c1b  = (const float*)d_in[15];
    const float* c2w  = (const float*)d_in[16];
    const float* c2b  = (const float*)d_in[17];
    const float* c3w  = (const float*)d_in[18];
    const float* c3b  = (const float*)d_in[19];

    float* wsf = (float*)d_ws;
    const size_t nA = 2048 * 128;
    float* A1e = wsf;
    float* A2e = wsf + nA;
    float* A1c = wsf + 2 * nA;
    float* A2c = wsf + 3 * nA;
    unsigned short* WtE = (unsigned short*)(wsf + 4 * nA);
    unsigned short* WtC = WtE + 128 * 128;

    float* xout = (float*)d_out;
    float* hout = xout + 8 * 256 * 3;

    prep_w<<<dim3(128), dim3(256), 0, stream>>>(e2w, c2w, WtE, WtC);
    prep_A<<<dim3(512), dim3(256), 0, stream>>>(h, e1w, e1b, c1w, c1b, A1e, A2e, A1c, A2c);
    egc_main<<<dim3(2048), dim3(512), 0, stream>>>(
        x, h, x0, pm, e1w, e2b, eiw, eib, n1w, n1b, n2w, n2b,
        c1w, c2b, c3w, c3b, A1e, A2e, A1c, A2c, WtE, WtC, xout, hout);
}